// Round 15
// baseline (684.539 us; speedup 1.0000x reference)
//
#include <hip/hip_runtime.h>
#include <hip/hip_bf16.h>
#include <math.h>

#define DEV __device__ __forceinline__

constexpr int D96 = 96;
constexpr int N96 = D96 * D96 * D96;      // 884736
constexpr int D48 = 48;
constexpr int N48 = D48 * D48 * D48;      // 110592

// Gaussian kernel (sigma=1, radius=3), normalized
#define GW0 0.3990502796524549f
#define GW1 0.2420362293761143f
#define GW2 0.05400558262251696f
#define GW3 0.004433048175243745f

typedef __attribute__((ext_vector_type(8))) short s16x8;
typedef __attribute__((ext_vector_type(4))) short s16x4;
typedef __attribute__((ext_vector_type(4))) float f32x4;
typedef __attribute__((ext_vector_type(16))) float f32x16;

DEV int clampi(int v, int lo, int hi) { return v < lo ? lo : (v > hi ? hi : v); }

DEV short f2bf(float f) { __hip_bfloat16 h = __float2bfloat16(f); short s; __builtin_memcpy(&s, &h, 2); return s; }
DEV float bf2f(short s) { __hip_bfloat16 h; __builtin_memcpy(&h, &s, 2); return __bfloat162float(h); }

// trilinear sample with clamped indices (mode='nearest')
DEV float trilerp(const float* __restrict__ img, int D, float cz, float cy, float cx)
{
    float fz = floorf(cz), fy = floorf(cy), fx = floorf(cx);
    float wz = cz - fz, wy = cy - fy, wx = cx - fx;
    int z0 = clampi((int)fz, 0, D - 1), z1 = clampi((int)fz + 1, 0, D - 1);
    int y0 = clampi((int)fy, 0, D - 1), y1 = clampi((int)fy + 1, 0, D - 1);
    int x0 = clampi((int)fx, 0, D - 1), x1 = clampi((int)fx + 1, 0, D - 1);
    float v000 = img[(z0 * D + y0) * D + x0], v001 = img[(z0 * D + y0) * D + x1];
    float v010 = img[(z0 * D + y1) * D + x0], v011 = img[(z0 * D + y1) * D + x1];
    float v100 = img[(z1 * D + y0) * D + x0], v101 = img[(z1 * D + y0) * D + x1];
    float v110 = img[(z1 * D + y1) * D + x0], v111 = img[(z1 * D + y1) * D + x1];
    float c00 = v000 + wx * (v001 - v000);
    float c01 = v010 + wx * (v011 - v010);
    float c10 = v100 + wx * (v101 - v100);
    float c11 = v110 + wx * (v111 - v110);
    float c0 = c00 + wy * (c01 - c00);
    float c1 = c10 + wy * (c11 - c10);
    return c0 + wz * (c1 - c0);
}

// ---------------- resize 96 -> 48 x2 inputs, trilinear antialias (4-tap 1,3,3,1 /8, edge renorm)
__global__ void k_downsample2x2(const float* __restrict__ srcA, const float* __restrict__ srcB,
                                float* __restrict__ dstA, float* __restrict__ dstB)
{
    int idx = blockIdx.x * blockDim.x + threadIdx.x;
    if (idx >= N48) return;
    const float* src = blockIdx.y ? srcB : srcA;
    float* dst = blockIdx.y ? dstB : dstA;
    int x = idx % D48, y = (idx / D48) % D48, z = idx / (D48 * D48);

    float wz[4], wy[4], wx[4];
    int jz[4], jy[4], jx[4];
    auto mk = [](int i, float* w, int* j) {
        const float base[4] = {0.125f, 0.375f, 0.375f, 0.125f};
        float s = 0.f;
        #pragma unroll
        for (int t = 0; t < 4; ++t) {
            int jj = 2 * i - 1 + t;
            bool v = (jj >= 0) && (jj < D96);
            j[t] = v ? jj : 0;
            w[t] = v ? base[t] : 0.f;
            s += w[t];
        }
        float inv = 1.f / s;
        #pragma unroll
        for (int t = 0; t < 4; ++t) w[t] *= inv;
    };
    mk(z, wz, jz); mk(y, wy, jy); mk(x, wx, jx);

    float acc = 0.f;
    #pragma unroll
    for (int a = 0; a < 4; ++a) {
        #pragma unroll
        for (int b = 0; b < 4; ++b) {
            float wab = wz[a] * wy[b];
            int rowoff = (jz[a] * D96 + jy[b]) * D96;
            #pragma unroll
            for (int c = 0; c < 4; ++c)
                acc += wab * wx[c] * src[rowoff + jx[c]];
        }
    }
    dst[idx] = acc;
}

// ---------------- vf upsample 48 -> 96 (trilinear, edge renorm) with *2 magnitude scale
__global__ void k_upsample_vf(const float* __restrict__ src, float* __restrict__ dst)
{
    int idx = blockIdx.x * blockDim.x + threadIdx.x;
    if (idx >= 3 * N96) return;
    int c = idx / N96;
    int s = idx - c * N96;
    int x = s % D96, y = (s / D96) % D96, z = s / (D96 * D96);

    auto mk = [](int i, int* j, float* w) {
        int k = i >> 1;
        if ((i & 1) == 0) { j[0] = k - 1; w[0] = 0.25f; j[1] = k; w[1] = 0.75f; }
        else              { j[0] = k;     w[0] = 0.75f; j[1] = k + 1; w[1] = 0.25f; }
        float sum = 0.f;
        #pragma unroll
        for (int t = 0; t < 2; ++t) {
            bool v = (j[t] >= 0) && (j[t] < D48);
            if (!v) { w[t] = 0.f; j[t] = 0; }
            sum += w[t];
        }
        float inv = 1.f / sum;
        w[0] *= inv; w[1] *= inv;
    };
    int jz[2], jy[2], jx[2]; float wz[2], wy[2], wx[2];
    mk(z, jz, wz); mk(y, jy, wy); mk(x, jx, wx);

    const float* p = src + (size_t)c * N48;
    float acc = 0.f;
    #pragma unroll
    for (int a = 0; a < 2; ++a)
        #pragma unroll
        for (int b = 0; b < 2; ++b) {
            float wab = wz[a] * wy[b];
            int rowoff = (jz[a] * D48 + jy[b]) * D48;
            acc += wab * (wx[0] * p[rowoff + jx[0]] + wx[1] * p[rowoff + jx[1]]);
        }
    dst[idx] = 2.f * acc;   // per-axis magnitude scale 96/48
}

// ---------------- trilinear warp, mode='nearest' (clamped indices)
__global__ void k_warp(const float* __restrict__ img, const float* __restrict__ vf,
                       float* __restrict__ out, int D)
{
    int N = D * D * D;
    int idx = blockIdx.x * blockDim.x + threadIdx.x;
    if (idx >= N) return;
    int x = idx % D, y = (idx / D) % D, z = idx / (D * D);
    out[idx] = trilerp(img, D, z + vf[idx], y + vf[N + idx], x + vf[2 * N + idx]);
}

// ---------------- demon forces + vf update (in place)
__global__ void k_forces(const float* __restrict__ warped, const float* __restrict__ fixed,
                         const float* __restrict__ mask, const float* __restrict__ spacing,
                         float* __restrict__ vf, int D, int maskD, float tau)
{
    int N = D * D * D;
    int idx = blockIdx.x * blockDim.x + threadIdx.x;
    if (idx >= N) return;
    int x = idx % D, y = (idx / D) % D, z = idx / (D * D);
    float w0 = warped[idx];
    float diff = w0 - fixed[idx];
    int sZ = D * D, sY = D;
    float gz = (z == 0) ? warped[idx + sZ] - w0 : (z == D - 1) ? w0 - warped[idx - sZ]
               : 0.5f * (warped[idx + sZ] - warped[idx - sZ]);
    float gy = (y == 0) ? warped[idx + sY] - w0 : (y == D - 1) ? w0 - warped[idx - sY]
               : 0.5f * (warped[idx + sY] - warped[idx - sY]);
    float gx = (x == 0) ? warped[idx + 1] - w0 : (x == D - 1) ? w0 - warped[idx - 1]
               : 0.5f * (warped[idx + 1] - warped[idx - 1]);
    gz /= spacing[0]; gy /= spacing[1]; gx /= spacing[2];
    float denom = gz * gz + gy * gy + gx * gx + diff * diff;
    float m;
    if (D == maskD) m = mask[idx];
    else {
        float r = (float)maskD / (float)D;
        int mz = clampi((int)((z + 0.5f) * r), 0, maskD - 1);
        int my = clampi((int)((y + 0.5f) * r), 0, maskD - 1);
        int mx = clampi((int)((x + 0.5f) * r), 0, maskD - 1);
        m = mask[(mz * maskD + my) * maskD + mx];
    }
    if (denom > 1e-9f) {
        float sc = tau * diff / denom * m;
        vf[idx]         += sc * gz;
        vf[N + idx]     += sc * gy;
        vf[2 * N + idx] += sc * gx;
    }
}

// ---------------- fused 3-axis separable 7-tap Gaussian, zero pad; 16^3 tile, 22^3 halo
__global__ __launch_bounds__(256, 2)
void k_smooth3(const float* __restrict__ src, float* __restrict__ dst, int D)
{
    __shared__ float B1[10648];       // 22^3 staged input
    __shared__ float B2[7744];        // 16*22*22 after z-pass
    float* B3 = B1;                   // 16*16*22 after y-pass (overlays dead B1)
    int nt = D >> 4;
    int b = blockIdx.x;
    int tx = b % nt, ty = (b / nt) % nt, tz = b / (nt * nt);
    int c = blockIdx.y;
    int N = D * D * D;
    const float* s = src + (size_t)c * N;
    float* d = dst + (size_t)c * N;
    int x0 = tx * 16, y0 = ty * 16, z0 = tz * 16;
    int tid = threadIdx.x;

    for (int l = tid; l < 10648; l += 256) {
        int xx = l % 22, yy = (l / 22) % 22, zz = l / 484;
        int gz = z0 + zz - 3, gy = y0 + yy - 3, gx = x0 + xx - 3;
        float v = 0.f;
        if ((unsigned)gz < (unsigned)D && (unsigned)gy < (unsigned)D && (unsigned)gx < (unsigned)D)
            v = s[((size_t)gz * D + gy) * D + gx];
        B1[l] = v;
    }
    __syncthreads();
    for (int l = tid; l < 16 * 484; l += 256) {
        int xx = l % 22, yy = (l / 22) % 22, zo = l / 484;
        int base = (zo + 3) * 484 + yy * 22 + xx;
        B2[l] = GW0 * B1[base]
              + GW1 * (B1[base - 484] + B1[base + 484])
              + GW2 * (B1[base - 968] + B1[base + 968])
              + GW3 * (B1[base - 1452] + B1[base + 1452]);
    }
    __syncthreads();
    for (int l = tid; l < 16 * 16 * 22; l += 256) {
        int xx = l % 22, yo = (l / 22) % 16, zo = l / 352;
        int base = zo * 484 + (yo + 3) * 22 + xx;
        B3[l] = GW0 * B2[base]
              + GW1 * (B2[base - 22] + B2[base + 22])
              + GW2 * (B2[base - 44] + B2[base + 44])
              + GW3 * (B2[base - 66] + B2[base + 66]);
    }
    __syncthreads();
    for (int l = tid; l < 4096; l += 256) {
        int xo = l % 16, yo = (l / 16) % 16, zo = l / 256;
        int base = zo * 352 + yo * 22 + xo + 3;
        float a = GW0 * B3[base]
                + GW1 * (B3[base - 1] + B3[base + 1])
                + GW2 * (B3[base - 2] + B3[base + 2])
                + GW3 * (B3[base - 3] + B3[base + 3]);
        d[((size_t)(z0 + zo) * D + (y0 + yo)) * D + (x0 + xo)] = a;
    }
}

// ---------------- fused warp + pack CNN input channels-last bf16:
// [vox][8] = {vf0,vf1,vf2,img*mask,warp(moving,vf),0,0,0}
__global__ void k_pack_warp(const float* __restrict__ vf, const float* __restrict__ image,
                            const float* __restrict__ mask, const float* __restrict__ moving,
                            short* __restrict__ xin8)
{
    int i = blockIdx.x * blockDim.x + threadIdx.x;
    if (i >= N96) return;
    int x = i % D96, y = (i / D96) % D96, z = i / (D96 * D96);
    float v0 = vf[i], v1 = vf[N96 + i], v2 = vf[2 * N96 + i];
    float w = trilerp(moving, D96, z + v0, y + v1, x + v2);
    s16x8 v;
    v[0] = f2bf(v0); v[1] = f2bf(v1); v[2] = f2bf(v2);
    v[3] = f2bf(image[i] * mask[i]); v[4] = f2bf(w);
    v[5] = 0; v[6] = 0; v[7] = 0;
    *reinterpret_cast<s16x8*>(&xin8[(size_t)i * 8]) = v;
}

// ---------------- all weight reorders in one launch.
// Layout: Wr[kg][COUTP][8] bf16, k = kg*8+j, (off,ci) = (k/CINP, k%CINP), off = dz*9+dy*3+dx
__global__ void k_wreorder_all(const float* __restrict__ w1, const float* __restrict__ w2,
                               const float* __restrict__ w3, const float* __restrict__ w4,
                               short* __restrict__ r1, short* __restrict__ r2,
                               short* __restrict__ r3, short* __restrict__ r4)
{
    int i = blockIdx.x * 256 + threadIdx.x;
    const int S1 = 7168, S2 = 55296, S3 = 55296, S4 = 13824;
    const float* w; short* r; int CIN, CINP, COUT, COUTP;
    int idx = i;
    if (idx < S1)              { w = w1; r = r1; CIN = 5;  CINP = 8;  COUT = 32; COUTP = 32; }
    else if ((idx -= S1) < S2) { w = w2; r = r2; CIN = 32; CINP = 32; COUT = 64; COUTP = 64; }
    else if ((idx -= S2) < S3) { w = w3; r = r3; CIN = 64; CINP = 64; COUT = 32; COUTP = 32; }
    else if ((idx -= S3) < S4) { w = w4; r = r4; CIN = 32; CINP = 32; COUT = 3;  COUTP = 16; }
    else return;
    int j = idx & 7;
    int co = (idx >> 3) % COUTP;
    int kg = idx / (8 * COUTP);
    int k = kg * 8 + j;
    int off = k / CINP, ci = k % CINP;
    float v = 0.f;
    if (co < COUT && off < 27 && ci < CIN)
        v = w[((size_t)co * CIN + ci) * 27 + off];
    r[idx] = f2bf(v);
}

// fast mish: x * tanh(softplus(x)) == x - 2x / ((1+e^x)^2 + 1)
DEV float mishf(float f)
{
    float e = __expf(f);
    float t = 1.f + e;
    float u = t * t + 1.f;
    return f - 2.f * f * __builtin_amdgcn_rcpf(u);
}

// ---------------- conv1: 8ch input, full 3-plane tile, 32x32x16 MFMA, fused stats,
// LDS-transpose epilogue; T5 setprio around MFMA cluster
__global__ __launch_bounds__(256, 4)
void k_conv1(const short* __restrict__ act, const short* __restrict__ Wr,
             short* __restrict__ outcl, float* __restrict__ part)
{
    constexpr int YH = 6, TN = 3, KS = 14;       // (27*8+15)/16
    constexpr int TILE_G = 3 * YH * 98;          // granules (G=1) -> 14112 shorts
    __shared__ __align__(16) short tile[TILE_G * 8];   // 28224 B (>= transpose 24576 B)
    float* red = (float*)tile;

    int b = blockIdx.x;
    int xcd = b & 7, bidx = b >> 3;
    int zblk = xcd * 12 + bidx / 24;
    int y0 = (bidx % 24) * 4;

    int tid = threadIdx.x;
    int lane = tid & 63, wave = tid >> 6;
    int ln31 = lane & 31, hi = lane >> 5;

    for (int i = tid; i < TILE_G; i += 256) {
        int xi = i % 98, yi = (i / 98) % YH, zi = i / (98 * YH);
        int gz = zblk + zi - 1, gy = y0 + yi - 1, gx = xi - 1;
        s16x8 v = {0, 0, 0, 0, 0, 0, 0, 0};
        if ((unsigned)gz < 96u && (unsigned)gy < 96u && (unsigned)gx < 96u)
            v = *reinterpret_cast<const s16x8*>(&act[(size_t)((gz * 96 + gy) * 96 + gx) * 8]);
        *reinterpret_cast<s16x8*>(&tile[i * 8]) = v;
    }
    __syncthreads();

    f32x16 acc[TN];
    #pragma unroll
    for (int i = 0; i < TN; ++i)
        #pragma unroll
        for (int e = 0; e < 16; ++e) acc[i][e] = 0.f;

    int xb_[TN];
    #pragma unroll
    for (int i = 0; i < TN; ++i) xb_[i] = i * 32 + ln31;

    __builtin_amdgcn_s_setprio(1);
    #pragma unroll
    for (int ks = 0; ks < KS; ++ks) {
        s16x8 a = *reinterpret_cast<const s16x8*>(&Wr[((size_t)(ks * 2 + hi) * 32 + ln31) * 8]);
        int off = ks * 2 + hi; if (off > 26) off = 26;   // padded k: weights are 0
        int dz = off / 9, r9 = off - dz * 9, dy = r9 / 3, dx = r9 - dy * 3;
        #pragma unroll
        for (int i = 0; i < TN; ++i) {
            int gi = (dz * YH + wave + dy) * 98 + xb_[i] + dx;
            s16x8 bf = *reinterpret_cast<const s16x8*>(&tile[gi * 8]);
            acc[i] = __builtin_amdgcn_mfma_f32_32x32x16_bf16(a, bf, acc[i], 0, 0, 0);
        }
    }
    __builtin_amdgcn_s_setprio(0);

    // stats (shfl over ln31)
    float st_s[16], st_q[16];
    #pragma unroll
    for (int j = 0; j < 16; ++j) { st_s[j] = 0.f; st_q[j] = 0.f; }
    #pragma unroll
    for (int i = 0; i < TN; ++i)
        #pragma unroll
        for (int e = 0; e < 16; ++e) {
            float v = acc[i][e];
            st_s[e] += v; st_q[e] += v * v;
        }
    #pragma unroll
    for (int j = 0; j < 16; ++j) {
        #pragma unroll
        for (int o = 1; o <= 16; o <<= 1) {
            st_s[j] += __shfl_xor(st_s[j], o);
            st_q[j] += __shfl_xor(st_q[j], o);
        }
    }

    // transpose epilogue: acc -> LDS [row][x][ch] (swizzled) -> coalesced stores
    __syncthreads();
    #pragma unroll
    for (int i = 0; i < TN; ++i) {
        int x = xb_[i];
        #pragma unroll
        for (int q = 0; q < 4; ++q) {
            s16x4 pk;
            #pragma unroll
            for (int r = 0; r < 4; ++r) pk[r] = f2bf(acc[i][q * 4 + r]);
            int bo = (((wave * 96 + x) * 32 + q * 8 + hi * 4) * 2) ^ ((x & 3) << 4);
            *reinterpret_cast<s16x4*>((char*)tile + bo) = pk;
        }
    }
    __syncthreads();
    for (int t = tid; t < 4 * 96 * 4; t += 256) {
        int gran = t & 3;
        int x = (t >> 2) % 96;
        int row = t / (4 * 96);
        int bo = (((row * 96 + x) * 32) * 2 + gran * 16) ^ ((x & 3) << 4);
        s16x8 v = *reinterpret_cast<const s16x8*>((char*)tile + bo);
        int vox = ((zblk * 96) + y0 + row) * 96 + x;
        *reinterpret_cast<s16x8*>(&outcl[(size_t)vox * 32 + gran * 8]) = v;
    }

    // block-level stats reduce via LDS overlay
    __syncthreads();
    if (ln31 == 0) {
        int base = (wave * 2 + hi) * 16;
        #pragma unroll
        for (int j = 0; j < 16; ++j) {
            red[(base + j) * 2]     = st_s[j];
            red[(base + j) * 2 + 1] = st_q[j];
        }
    }
    __syncthreads();
    if (tid < 64) {
        int c = tid >> 1, sel = tid & 1;
        int q = (c >> 3) & 3, hic = (c >> 2) & 1, r = c & 3;
        int j = q * 4 + r;
        float v = 0.f;
        #pragma unroll
        for (int w = 0; w < 4; ++w)
            v += red[((w * 2 + hic) * 16 + j) * 2 + sel];
        part[((size_t)c * gridDim.x + blockIdx.x) * 2 + sel] = v;
    }
}

// ---------------- conv2: 32->64, XCD-aligned paired cout-half blocks, 32B-pair staging,
// register-precomputed B addresses; T5 setprio around MFMA cluster
__global__ __launch_bounds__(256, 4)
void k_conv_c2(const short* __restrict__ act, const short* __restrict__ Wr,
               short* __restrict__ outcl, float* __restrict__ part)
{
    constexpr int TN = 3, YH = 6;
    __shared__ __align__(16) short tile[YH * 98 * 32];   // 37632 B (>= TR 24576 B)
    float* red = (float*)tile;

    int bb = blockIdx.x;
    int xcd = bb & 7;                         // physical XCD (hw round-robin)
    int ch = (bb >> 3) & 1;                   // cout half; bb and bb+8 share a tile + XCD
    int idx = bb >> 4;                        // tile within slab, 0..287
    int zblk = xcd * 12 + idx / 24;
    int y0 = (idx % 24) * 4;
    int tileid = xcd * 288 + idx;             // 0..2303 for stats partials

    int tid = threadIdx.x;
    int lane = tid & 63, wave = tid >> 6;
    int ln31 = lane & 31, hi = lane >> 5;

    int xb_[TN];
    #pragma unroll
    for (int i = 0; i < TN; ++i) xb_[i] = i * 32 + ln31;

    // precomputed B-tile byte addresses (dy=0); dy adds imm offset dy*6272
    int baddr[TN][3][2];
    #pragma unroll
    for (int i = 0; i < TN; ++i)
        #pragma unroll
        for (int dx = 0; dx < 3; ++dx) {
            int xi = xb_[i] + dx;
            int sw = (xi >> 1) & 3;
            #pragma unroll
            for (int gs = 0; gs < 2; ++gs)
                baddr[i][dx][gs] = ((wave * 98 + xi) * 4 + ((gs * 2 + hi) ^ sw)) * 16;
        }

    f32x16 acc[TN];
    #pragma unroll
    for (int i = 0; i < TN; ++i)
        #pragma unroll
        for (int e = 0; e < 16; ++e) acc[i][e] = 0.f;

    for (int p = 0; p < 3; ++p) {
        int gz = zblk + p - 1;
        __syncthreads();
        // stage 6x98 x 32ch plane, 32B (2 granules) per lane-iter
        #pragma unroll
        for (int it = 0; it < 5; ++it) {
            int i = it * 256 + tid;
            if (i < 1176) {
                int g2 = i & 1, x2 = i >> 1;
                int xi = x2 % 98, yi = x2 / 98;
                int gy = y0 + yi - 1, gx = xi - 1;
                s16x8 v0 = {0, 0, 0, 0, 0, 0, 0, 0}, v1 = v0;
                if ((unsigned)gz < 96u && (unsigned)gy < 96u && (unsigned)gx < 96u) {
                    const short* sp = &act[(size_t)((gz * 96 + gy) * 96 + gx) * 32 + g2 * 16];
                    v0 = *reinterpret_cast<const s16x8*>(sp);
                    v1 = *reinterpret_cast<const s16x8*>(sp + 8);
                }
                int s0 = (g2 * 2) ^ ((xi >> 1) & 3);
                short* dp = &tile[((yi * 98 + xi) << 2) * 8];
                *reinterpret_cast<s16x8*>(&dp[s0 * 8]) = v0;
                *reinterpret_cast<s16x8*>(&dp[(s0 ^ 1) * 8]) = v1;
            }
        }
        __syncthreads();
        int kgbase = p * 36;
        __builtin_amdgcn_s_setprio(1);
        #pragma unroll
        for (int ks = 0; ks < 18; ++ks) {
            constexpr int offt[18] = {0,0,1,1,2,2,3,3,4,4,5,5,6,6,7,7,8,8};
            const int off = offt[ks], gs = ks & 1;
            int kg = kgbase + off * 4 + gs * 2 + hi;
            s16x8 A = *reinterpret_cast<const s16x8*>(
                &Wr[((size_t)kg * 64 + ch * 32 + ln31) * 8]);
            const int dy = off / 3, dx = off % 3;
            #pragma unroll
            for (int i = 0; i < TN; ++i) {
                s16x8 bf = *reinterpret_cast<const s16x8*>(
                    (const char*)tile + baddr[i][dx][gs] + dy * 6272);
                acc[i] = __builtin_amdgcn_mfma_f32_32x32x16_bf16(A, bf, acc[i], 0, 0, 0);
            }
        }
        __builtin_amdgcn_s_setprio(0);
    }

    // stats; local channel = (e&3) + 8*(e>>2) + 4*hi
    float st_s[16], st_q[16];
    #pragma unroll
    for (int j = 0; j < 16; ++j) { st_s[j] = 0.f; st_q[j] = 0.f; }
    #pragma unroll
    for (int i = 0; i < TN; ++i)
        #pragma unroll
        for (int e = 0; e < 16; ++e) {
            float v = acc[i][e];
            st_s[e] += v; st_q[e] += v * v;
        }
    #pragma unroll
    for (int j = 0; j < 16; ++j) {
        #pragma unroll
        for (int o = 1; o <= 16; o <<= 1) {
            st_s[j] += __shfl_xor(st_s[j], o);
            st_q[j] += __shfl_xor(st_q[j], o);
        }
    }

    // transpose epilogue -> coalesced 64B/vox-half stores
    __syncthreads();
    #pragma unroll
    for (int i = 0; i < TN; ++i) {
        int x = xb_[i];
        #pragma unroll
        for (int q = 0; q < 4; ++q) {
            s16x4 pk;
            #pragma unroll
            for (int r = 0; r < 4; ++r) pk[r] = f2bf(acc[i][q * 4 + r]);
            int bo = (((wave * 96 + x) * 32 + q * 8 + hi * 4) * 2) ^ ((x & 3) << 4);
            *reinterpret_cast<s16x4*>((char*)tile + bo) = pk;
        }
    }
    __syncthreads();
    for (int t = tid; t < 4 * 96 * 4; t += 256) {
        int gran = t & 3;
        int x = (t >> 2) % 96;
        int row = t / (4 * 96);
        int bo = (((row * 96 + x) * 32) * 2 + gran * 16) ^ ((x & 3) << 4);
        s16x8 v = *reinterpret_cast<const s16x8*>((char*)tile + bo);
        int vox = ((zblk * 96) + y0 + row) * 96 + x;
        *reinterpret_cast<s16x8*>(&outcl[(size_t)vox * 64 + ch * 32 + gran * 8]) = v;
    }

    // block-level stats reduce
    __syncthreads();
    if (ln31 == 0) {
        int base = (wave * 2 + hi) * 16;
        #pragma unroll
        for (int j = 0; j < 16; ++j) {
            red[(base + j) * 2]     = st_s[j];
            red[(base + j) * 2 + 1] = st_q[j];
        }
    }
    __syncthreads();
    if (tid < 64) {
        int c = tid >> 1, sel = tid & 1;
        int q = (c >> 3) & 3, hic = (c >> 2) & 1, r = c & 3;
        int j = q * 4 + r;
        float v = 0.f;
        #pragma unroll
        for (int w = 0; w < 4; ++w)
            v += red[((w * 2 + hic) * 16 + j) * 2 + sel];
        part[((size_t)(ch * 32 + c) * 2304 + tileid) * 2 + sel] = v;
    }
}

// ---------------- conv3: 64->32, XCD-aligned paired cout-half blocks, 16x16x32 MFMA,
// 32B-pair staging + register-precomputed B addresses; T5 setprio around MFMA cluster
__global__ __launch_bounds__(256, 4)
void k_conv_c3(const short* __restrict__ act, const short* __restrict__ Wr,
               short* __restrict__ outcl, float* __restrict__ part)
{
    constexpr int YH = 6;
    __shared__ __align__(16) short tile[YH * 98 * 32];   // 37632 B (>= TR 12288 B)
    float* red = (float*)tile;

    int bb = blockIdx.x;
    int xcd = bb & 7;                         // physical XCD
    int ch = (bb >> 3) & 1;                   // cout half (16 couts)
    int idx = bb >> 4;
    int zblk = xcd * 12 + idx / 24;
    int y0 = (idx % 24) * 4;
    int tileid = xcd * 288 + idx;

    int tid = threadIdx.x;
    int lane = tid & 63, wave = tid >> 6;
    int ln15 = lane & 15, lg = lane >> 4;

    // precomputed B-tile byte addresses (dy via imm offset)
    int baddr[6][3];
    #pragma unroll
    for (int i = 0; i < 6; ++i)
        #pragma unroll
        for (int dx = 0; dx < 3; ++dx) {
            int xi = i * 16 + ln15 + dx;
            baddr[i][dx] = ((wave * 98 + xi) * 4 + (lg ^ ((xi >> 1) & 3))) * 16;
        }

    f32x4 acc[6];
    #pragma unroll
    for (int i = 0; i < 6; ++i) acc[i] = {0.f, 0.f, 0.f, 0.f};

    for (int p = 0; p < 3; ++p) {
        int gz = zblk + p - 1;
        for (int h = 0; h < 2; ++h) {
            __syncthreads();
            #pragma unroll
            for (int it = 0; it < 5; ++it) {
                int i = it * 256 + tid;
                if (i < 1176) {
                    int g2 = i & 1, x2 = i >> 1;
                    int xi = x2 % 98, yi = x2 / 98;
                    int gy = y0 + yi - 1, gx = xi - 1;
                    s16x8 v0 = {0, 0, 0, 0, 0, 0, 0, 0}, v1 = v0;
                    if ((unsigned)gz < 96u && (unsigned)gy < 96u && (unsigned)gx < 96u) {
                        const short* sp = &act[(size_t)((gz * 96 + gy) * 96 + gx) * 64
                                               + (h * 4 + g2 * 2) * 8];
                        v0 = *reinterpret_cast<const s16x8*>(sp);
                        v1 = *reinterpret_cast<const s16x8*>(sp + 8);
                    }
                    int s0 = (g2 * 2) ^ ((xi >> 1) & 3);
                    short* dp = &tile[((yi * 98 + xi) << 2) * 8];
                    *reinterpret_cast<s16x8*>(&dp[s0 * 8]) = v0;
                    *reinterpret_cast<s16x8*>(&dp[(s0 ^ 1) * 8]) = v1;
                }
            }
            __syncthreads();
            __builtin_amdgcn_s_setprio(1);
            #pragma unroll
            for (int off = 0; off < 9; ++off) {
                int kg = (p * 9 + off) * 8 + h * 4 + lg;
                s16x8 A = *reinterpret_cast<const s16x8*>(
                    &Wr[((size_t)kg * 32 + ch * 16 + ln15) * 8]);
                const int dy = off / 3, dx = off % 3;
                #pragma unroll
                for (int i = 0; i < 6; ++i) {
                    s16x8 bf = *reinterpret_cast<const s16x8*>(
                        (const char*)tile + baddr[i][dx] + dy * 6272);
                    acc[i] = __builtin_amdgcn_mfma_f32_16x16x32_bf16(A, bf, acc[i], 0, 0, 0);
                }
            }
            __builtin_amdgcn_s_setprio(0);
        }
    }

    // stats; local channel = lg*4 + r; reduce over the 16 vox lanes (ln15)
    float st_s[4], st_q[4];
    #pragma unroll
    for (int j = 0; j < 4; ++j) { st_s[j] = 0.f; st_q[j] = 0.f; }
    #pragma unroll
    for (int i = 0; i < 6; ++i)
        #pragma unroll
        for (int r = 0; r < 4; ++r) {
            float v = acc[i][r];
            st_s[r] += v; st_q[r] += v * v;
        }
    #pragma unroll
    for (int j = 0; j < 4; ++j) {
        #pragma unroll
        for (int o = 1; o <= 8; o <<= 1) {
            st_s[j] += __shfl_xor(st_s[j], o);
            st_q[j] += __shfl_xor(st_q[j], o);
        }
    }

    // transpose epilogue: [row][x][16ch] swizzled -> coalesced 32B/vox stores (paired halves)
    __syncthreads();
    #pragma unroll
    for (int i = 0; i < 6; ++i) {
        int x = i * 16 + ln15;
        s16x4 pk;
        #pragma unroll
        for (int r = 0; r < 4; ++r) pk[r] = f2bf(acc[i][r]);
        int bo = (((wave * 96 + x) * 16 + lg * 4) * 2) ^ ((x & 3) << 4);
        *reinterpret_cast<s16x4*>((char*)tile + bo) = pk;
    }
    __syncthreads();
    for (int t = tid; t < 4 * 96 * 2; t += 256) {
        int gran = t & 1;
        int x = (t >> 1) % 96;
        int row = t / (2 * 96);
        int bo = (((row * 96 + x) * 16) * 2 + gran * 16) ^ ((x & 3) << 4);
        s16x8 v = *reinterpret_cast<const s16x8*>((char*)tile + bo);
        int vox = ((zblk * 96) + y0 + row) * 96 + x;
        *reinterpret_cast<s16x8*>(&outcl[(size_t)vox * 32 + ch * 16 + gran * 8]) = v;
    }

    // block-level stats reduce: red[wave][lg][4]
    __syncthreads();
    if (ln15 == 0) {
        int base = (wave * 4 + lg) * 4;
        #pragma unroll
        for (int j = 0; j < 4; ++j) {
            red[(base + j) * 2]     = st_s[j];
            red[(base + j) * 2 + 1] = st_q[j];
        }
    }
    __syncthreads();
    if (tid < 32) {
        int c = tid >> 1, sel = tid & 1;     // c = local channel 0..15 = lg*4+r
        float v = 0.f;
        #pragma unroll
        for (int w = 0; w < 4; ++w)
            v += red[((w * 4 + (c >> 2)) * 4 + (c & 3)) * 2 + sel];
        part[((size_t)(ch * 16 + c) * 2304 + tileid) * 2 + sel] = v;
    }
}

// ---------------- conv4: 32->3 via 16x16x32 MFMA (COUTP=16), 32B staging + precomp addrs,
// fused vf-add + vf copy; T5 setprio around MFMA cluster
__global__ __launch_bounds__(256, 4)
void k_conv4(const short* __restrict__ act, const short* __restrict__ Wr,
             const float* __restrict__ bias, const float* __restrict__ vf,
             float* __restrict__ corr, float* __restrict__ outvf)
{
    constexpr int YH = 6;
    __shared__ __align__(16) short tile[YH * 98 * 32];

    int b = blockIdx.x;
    int xcd = b & 7, bidx = b >> 3;
    int zblk = xcd * 12 + bidx / 24;
    int y0 = (bidx % 24) * 4;

    int tid = threadIdx.x;
    int lane = tid & 63, wave = tid >> 6;
    int ln15 = lane & 15, lg = lane >> 4;

    int baddr[6][3];
    #pragma unroll
    for (int i = 0; i < 6; ++i)
        #pragma unroll
        for (int dx = 0; dx < 3; ++dx) {
            int xi = i * 16 + ln15 + dx;
            baddr[i][dx] = ((wave * 98 + xi) * 4 + (lg ^ ((xi >> 1) & 3))) * 16;
        }

    f32x4 acc[6];
    #pragma unroll
    for (int i = 0; i < 6; ++i) acc[i] = {0.f, 0.f, 0.f, 0.f};

    for (int p = 0; p < 3; ++p) {
        int gz = zblk + p - 1;
        __syncthreads();
        #pragma unroll
        for (int it = 0; it < 5; ++it) {
            int i = it * 256 + tid;
            if (i < 1176) {
                int g2 = i & 1, x2 = i >> 1;
                int xi = x2 % 98, yi = x2 / 98;
                int gy = y0 + yi - 1, gx = xi - 1;
                s16x8 v0 = {0, 0, 0, 0, 0, 0, 0, 0}, v1 = v0;
                if ((unsigned)gz < 96u && (unsigned)gy < 96u && (unsigned)gx < 96u) {
                    const short* sp = &act[(size_t)((gz * 96 + gy) * 96 + gx) * 32 + g2 * 16];
                    v0 = *reinterpret_cast<const s16x8*>(sp);
                    v1 = *reinterpret_cast<const s16x8*>(sp + 8);
                }
                int s0 = (g2 * 2) ^ ((xi >> 1) & 3);
                short* dp = &tile[((yi * 98 + xi) << 2) * 8];
                *reinterpret_cast<s16x8*>(&dp[s0 * 8]) = v0;
                *reinterpret_cast<s16x8*>(&dp[(s0 ^ 1) * 8]) = v1;
            }
        }
        __syncthreads();
        __builtin_amdgcn_s_setprio(1);
        #pragma unroll
        for (int ks = 0; ks < 9; ++ks) {
            int kg = (p * 9 + ks) * 4 + lg;
            s16x8 a = *reinterpret_cast<const s16x8*>(&Wr[((size_t)kg * 16 + ln15) * 8]);
            const int dy = ks / 3, dx = ks % 3;
            #pragma unroll
            for (int i = 0; i < 6; ++i) {
                s16x8 bf = *reinterpret_cast<const s16x8*>(
                    (const char*)tile + baddr[i][dx] + dy * 6272);
                acc[i] = __builtin_amdgcn_mfma_f32_16x16x32_bf16(a, bf, acc[i], 0, 0, 0);
            }
        }
        __builtin_amdgcn_s_setprio(0);
    }
    // D: col=ln15 (vox), row = lg*4 + r (cout). Rows 0..2 live on lg==0.
    if (lg == 0) {
        #pragma unroll
        for (int i = 0; i < 6; ++i) {
            int vox = ((zblk * 96) + y0 + wave) * 96 + i * 16 + ln15;
            #pragma unroll
            for (int r = 0; r < 3; ++r) {
                float v = vf[(size_t)r * N96 + vox];
                corr[(size_t)r * N96 + vox] = acc[i][r] + bias[r] + v;
                outvf[(size_t)r * N96 + vox] = v;
            }
        }
    }
}

// ---------------- instance-norm apply + mish, channels-last, in place
template <int C>
__global__ void k_norm_mish_cl(short* __restrict__ x, const float* __restrict__ stats)
{
    constexpr int G8 = C / 8;
    int gt = blockIdx.x * 256 + threadIdx.x;
    int cg = threadIdx.x % G8;       // fixed per thread (stride divisible by G8)
    float mean[8], inv[8];
    #pragma unroll
    for (int j = 0; j < 8; ++j) { mean[j] = stats[2 * (cg * 8 + j)]; inv[j] = stats[2 * (cg * 8 + j) + 1]; }
    const int TGn = N96 * G8;
    int stride = gridDim.x * 256;
    for (int i = gt; i < TGn; i += stride) {
        s16x8 v = *reinterpret_cast<const s16x8*>(&x[(size_t)i * 8]);
        #pragma unroll
        for (int j = 0; j < 8; ++j)
            v[j] = f2bf(mishf((bf2f(v[j]) - mean[j]) * inv[j]));
        *reinterpret_cast<s16x8*>(&x[(size_t)i * 8]) = v;
    }
}

// stage 2: reduce per-block partials/channel -> mean + inv_std
__global__ void k_stats_reduce(const float* __restrict__ part, float* __restrict__ stats,
                               int G, int N)
{
    int c = blockIdx.x;
    int t = threadIdx.x;
    float s = 0.f, s2 = 0.f;
    for (int i = t; i < G; i += blockDim.x) {
        s  += part[((size_t)c * G + i) * 2];
        s2 += part[((size_t)c * G + i) * 2 + 1];
    }
    #pragma unroll
    for (int o = 32; o > 0; o >>= 1) { s += __shfl_down(s, o); s2 += __shfl_down(s2, o); }
    __shared__ float a[4], b[4];
    int lane = t & 63, wid = t >> 6;
    if (lane == 0) { a[wid] = s; b[wid] = s2; }
    __syncthreads();
    if (t == 0) {
        float ss = a[0] + a[1] + a[2] + a[3];
        float qq = b[0] + b[1] + b[2] + b[3];
        float mean = ss / (float)N;
        float var = qq / (float)N - mean * mean;
        stats[2 * c] = mean;
        stats[2 * c + 1] = rsqrtf(var + 1e-5f);
    }
}

extern "C" void kernel_launch(void* const* d_in, const int* in_sizes, int n_in,
                              void* d_out, int out_size, void* d_ws, size_t ws_size,
                              hipStream_t stream)
{
    const float* image   = (const float*)d_in[0];
    const float* mask    = (const float*)d_in[1];
    const float* moving  = (const float*)d_in[2];
    const float* spacing = (const float*)d_in[3];
    const float* w1 = (const float*)d_in[4];
    const float* w2 = (const float*)d_in[5];
    const float* w3 = (const float*)d_in[6];
    const float* w4 = (const float*)d_in[7];
    const float* b4 = (const float*)d_in[8];
    float* out = (float*)d_out;

    char* ws = (char*)d_ws;
    size_t off = 0;
    auto alloc = [&](size_t bytes) -> char* {
        char* p = ws + off;
        off += (bytes + 255) & ~(size_t)255;
        return p;
    };
    float* f48   = (float*)alloc((size_t)N48 * 4);
    float* mv48  = (float*)alloc((size_t)N48 * 4);
    float* vfA48 = (float*)alloc((size_t)3 * N48 * 4);
    float* vfB48 = (float*)alloc((size_t)3 * N48 * 4);
    float* wrp48 = (float*)alloc((size_t)N48 * 4);
    float* vfA96 = (float*)alloc((size_t)3 * N96 * 4);
    float* vfB96 = (float*)alloc((size_t)3 * N96 * 4);
    float* vfC96 = (float*)alloc((size_t)3 * N96 * 4);
    float* wrp96 = (float*)alloc((size_t)N96 * 4);
    short* xin8  = (short*)alloc((size_t)8 * N96 * 2);
    short* y1    = (short*)alloc((size_t)32 * N96 * 2);
    short* y2    = (short*)alloc((size_t)64 * N96 * 2);
    short* wr1   = (short*)alloc((size_t)7168 * 2);
    short* wr2   = (short*)alloc((size_t)55296 * 2);
    short* wr3   = (short*)alloc((size_t)55296 * 2);
    short* wr4   = (short*)alloc((size_t)13824 * 2);
    float* part  = (float*)alloc((size_t)64 * 2304 * 2 * 4);
    float* stats = (float*)alloc((size_t)64 * 2 * 4);

    const int B = 256;
    const int g48  = (N48 + B - 1) / B;
    const int g96  = (N96 + B - 1) / B;
    const int g96c = (3 * N96 + B - 1) / B;

    // ---- all weight reorders (one launch) ----
    k_wreorder_all<<<(131584 + 255) / 256, B, 0, stream>>>(w1, w2, w3, w4, wr1, wr2, wr3, wr4);

    // ---- Level 0 (48^3) ----
    k_downsample2x2<<<dim3(g48, 2), B, 0, stream>>>(image, moving, f48, mv48);
    hipMemsetAsync(vfA48, 0, (size_t)3 * N48 * 4, stream);
    float* cur = vfA48; float* oth = vfB48;
    for (int it = 0; it < 2; ++it) {
        k_warp<<<g48, B, 0, stream>>>(mv48, cur, wrp48, D48);
        k_forces<<<g48, B, 0, stream>>>(wrp48, f48, mask, spacing, cur, D48, D96, 2.0f);
        k_smooth3<<<dim3(27, 3), B, 0, stream>>>(cur, oth, D48);
        float* tmp = cur; cur = oth; oth = tmp;
    }

    // ---- Level 1 (96^3) ----
    k_upsample_vf<<<g96c, B, 0, stream>>>(cur, vfA96);
    float* cur9 = vfA96; float* oth9 = vfB96;
    for (int it = 0; it < 2; ++it) {
        k_warp<<<g96, B, 0, stream>>>(moving, cur9, wrp96, D96);
        k_forces<<<g96, B, 0, stream>>>(wrp96, image, mask, spacing, cur9, D96, D96, 2.0f);
        k_smooth3<<<dim3(216, 3), B, 0, stream>>>(cur9, oth9, D96);
        float* tmp = cur9; cur9 = oth9; oth9 = tmp;
    }
    // cur9 == vfA96 here (final vf)

    // ---- CNN ----
    k_pack_warp<<<g96, B, 0, stream>>>(cur9, image, mask, moving, xin8);

    // conv1: 8(5)->32, stats fused; then reduce + norm
    k_conv1<<<2304, B, 0, stream>>>(xin8, wr1, y1, part);
    k_stats_reduce<<<32, B, 0, stream>>>(part, stats, 2304, N96);
    k_norm_mish_cl<32><<<2048, B, 0, stream>>>(y1, stats);

    // conv2: 32->64, XCD-aligned paired cout-half blocks
    k_conv_c2<<<4608, B, 0, stream>>>(y1, wr2, y2, part);
    k_stats_reduce<<<64, B, 0, stream>>>(part, stats, 2304, N96);
    k_norm_mish_cl<64><<<2048, B, 0, stream>>>(y2, stats);

    // conv3: 64->32, XCD-aligned paired cout-half blocks (output reuses y1)
    k_conv_c3<<<4608, B, 0, stream>>>(y2, wr3, y1, part);
    k_stats_reduce<<<32, B, 0, stream>>>(part, stats, 2304, N96);
    k_norm_mish_cl<32><<<2048, B, 0, stream>>>(y1, stats);

    // conv4: 32->3 (+bias), f32 out = correction + vf; also emits vf output copy
    k_conv4<<<2304, B, 0, stream>>>(y1, wr4, b4, cur9, vfC96, out + (size_t)4 * N96);

    // corrected_vf = smooth3d(vf + correction) -> straight to d_out
    k_smooth3<<<dim3(216, 3), B, 0, stream>>>(vfC96, out + N96, D96);

    // corrected_warped_moving
    k_warp<<<g96, B, 0, stream>>>(moving, out + N96, out, D96);
}

// Round 16
// 678.713 us; speedup vs baseline: 1.0086x; 1.0086x over previous
//
#include <hip/hip_runtime.h>
#include <hip/hip_bf16.h>
#include <math.h>

#define DEV __device__ __forceinline__

constexpr int D96 = 96;
constexpr int N96 = D96 * D96 * D96;      // 884736
constexpr int D48 = 48;
constexpr int N48 = D48 * D48 * D48;      // 110592

// Gaussian kernel (sigma=1, radius=3), normalized
#define GW0 0.3990502796524549f
#define GW1 0.2420362293761143f
#define GW2 0.05400558262251696f
#define GW3 0.004433048175243745f

typedef __attribute__((ext_vector_type(8))) short s16x8;
typedef __attribute__((ext_vector_type(4))) short s16x4;
typedef __attribute__((ext_vector_type(4))) float f32x4;
typedef __attribute__((ext_vector_type(16))) float f32x16;

DEV int clampi(int v, int lo, int hi) { return v < lo ? lo : (v > hi ? hi : v); }

DEV short f2bf(float f) { __hip_bfloat16 h = __float2bfloat16(f); short s; __builtin_memcpy(&s, &h, 2); return s; }
DEV float bf2f(short s) { __hip_bfloat16 h; __builtin_memcpy(&h, &s, 2); return __bfloat162float(h); }

// trilinear sample with clamped indices (mode='nearest')
DEV float trilerp(const float* __restrict__ img, int D, float cz, float cy, float cx)
{
    float fz = floorf(cz), fy = floorf(cy), fx = floorf(cx);
    float wz = cz - fz, wy = cy - fy, wx = cx - fx;
    int z0 = clampi((int)fz, 0, D - 1), z1 = clampi((int)fz + 1, 0, D - 1);
    int y0 = clampi((int)fy, 0, D - 1), y1 = clampi((int)fy + 1, 0, D - 1);
    int x0 = clampi((int)fx, 0, D - 1), x1 = clampi((int)fx + 1, 0, D - 1);
    float v000 = img[(z0 * D + y0) * D + x0], v001 = img[(z0 * D + y0) * D + x1];
    float v010 = img[(z0 * D + y1) * D + x0], v011 = img[(z0 * D + y1) * D + x1];
    float v100 = img[(z1 * D + y0) * D + x0], v101 = img[(z1 * D + y0) * D + x1];
    float v110 = img[(z1 * D + y1) * D + x0], v111 = img[(z1 * D + y1) * D + x1];
    float c00 = v000 + wx * (v001 - v000);
    float c01 = v010 + wx * (v011 - v010);
    float c10 = v100 + wx * (v101 - v100);
    float c11 = v110 + wx * (v111 - v110);
    float c0 = c00 + wy * (c01 - c00);
    float c1 = c10 + wy * (c11 - c10);
    return c0 + wz * (c1 - c0);
}

// ---------------- resize 96 -> 48 x2 inputs, trilinear antialias (4-tap 1,3,3,1 /8, edge renorm)
__global__ void k_downsample2x2(const float* __restrict__ srcA, const float* __restrict__ srcB,
                                float* __restrict__ dstA, float* __restrict__ dstB)
{
    int idx = blockIdx.x * blockDim.x + threadIdx.x;
    if (idx >= N48) return;
    const float* src = blockIdx.y ? srcB : srcA;
    float* dst = blockIdx.y ? dstB : dstA;
    int x = idx % D48, y = (idx / D48) % D48, z = idx / (D48 * D48);

    float wz[4], wy[4], wx[4];
    int jz[4], jy[4], jx[4];
    auto mk = [](int i, float* w, int* j) {
        const float base[4] = {0.125f, 0.375f, 0.375f, 0.125f};
        float s = 0.f;
        #pragma unroll
        for (int t = 0; t < 4; ++t) {
            int jj = 2 * i - 1 + t;
            bool v = (jj >= 0) && (jj < D96);
            j[t] = v ? jj : 0;
            w[t] = v ? base[t] : 0.f;
            s += w[t];
        }
        float inv = 1.f / s;
        #pragma unroll
        for (int t = 0; t < 4; ++t) w[t] *= inv;
    };
    mk(z, wz, jz); mk(y, wy, jy); mk(x, wx, jx);

    float acc = 0.f;
    #pragma unroll
    for (int a = 0; a < 4; ++a) {
        #pragma unroll
        for (int b = 0; b < 4; ++b) {
            float wab = wz[a] * wy[b];
            int rowoff = (jz[a] * D96 + jy[b]) * D96;
            #pragma unroll
            for (int c = 0; c < 4; ++c)
                acc += wab * wx[c] * src[rowoff + jx[c]];
        }
    }
    dst[idx] = acc;
}

// ---------------- vf upsample 48 -> 96 (trilinear, edge renorm) with *2 magnitude scale
__global__ void k_upsample_vf(const float* __restrict__ src, float* __restrict__ dst)
{
    int idx = blockIdx.x * blockDim.x + threadIdx.x;
    if (idx >= 3 * N96) return;
    int c = idx / N96;
    int s = idx - c * N96;
    int x = s % D96, y = (s / D96) % D96, z = s / (D96 * D96);

    auto mk = [](int i, int* j, float* w) {
        int k = i >> 1;
        if ((i & 1) == 0) { j[0] = k - 1; w[0] = 0.25f; j[1] = k; w[1] = 0.75f; }
        else              { j[0] = k;     w[0] = 0.75f; j[1] = k + 1; w[1] = 0.25f; }
        float sum = 0.f;
        #pragma unroll
        for (int t = 0; t < 2; ++t) {
            bool v = (j[t] >= 0) && (j[t] < D48);
            if (!v) { w[t] = 0.f; j[t] = 0; }
            sum += w[t];
        }
        float inv = 1.f / sum;
        w[0] *= inv; w[1] *= inv;
    };
    int jz[2], jy[2], jx[2]; float wz[2], wy[2], wx[2];
    mk(z, jz, wz); mk(y, jy, wy); mk(x, jx, wx);

    const float* p = src + (size_t)c * N48;
    float acc = 0.f;
    #pragma unroll
    for (int a = 0; a < 2; ++a)
        #pragma unroll
        for (int b = 0; b < 2; ++b) {
            float wab = wz[a] * wy[b];
            int rowoff = (jz[a] * D48 + jy[b]) * D48;
            acc += wab * (wx[0] * p[rowoff + jx[0]] + wx[1] * p[rowoff + jx[1]]);
        }
    dst[idx] = 2.f * acc;   // per-axis magnitude scale 96/48
}

// ---------------- trilinear warp, mode='nearest' (clamped indices)
__global__ void k_warp(const float* __restrict__ img, const float* __restrict__ vf,
                       float* __restrict__ out, int D)
{
    int N = D * D * D;
    int idx = blockIdx.x * blockDim.x + threadIdx.x;
    if (idx >= N) return;
    int x = idx % D, y = (idx / D) % D, z = idx / (D * D);
    out[idx] = trilerp(img, D, z + vf[idx], y + vf[N + idx], x + vf[2 * N + idx]);
}

// ---------------- demon forces + vf update (in place)
__global__ void k_forces(const float* __restrict__ warped, const float* __restrict__ fixed,
                         const float* __restrict__ mask, const float* __restrict__ spacing,
                         float* __restrict__ vf, int D, int maskD, float tau)
{
    int N = D * D * D;
    int idx = blockIdx.x * blockDim.x + threadIdx.x;
    if (idx >= N) return;
    int x = idx % D, y = (idx / D) % D, z = idx / (D * D);
    float w0 = warped[idx];
    float diff = w0 - fixed[idx];
    int sZ = D * D, sY = D;
    float gz = (z == 0) ? warped[idx + sZ] - w0 : (z == D - 1) ? w0 - warped[idx - sZ]
               : 0.5f * (warped[idx + sZ] - warped[idx - sZ]);
    float gy = (y == 0) ? warped[idx + sY] - w0 : (y == D - 1) ? w0 - warped[idx - sY]
               : 0.5f * (warped[idx + sY] - warped[idx - sY]);
    float gx = (x == 0) ? warped[idx + 1] - w0 : (x == D - 1) ? w0 - warped[idx - 1]
               : 0.5f * (warped[idx + 1] - warped[idx - 1]);
    gz /= spacing[0]; gy /= spacing[1]; gx /= spacing[2];
    float denom = gz * gz + gy * gy + gx * gx + diff * diff;
    float m;
    if (D == maskD) m = mask[idx];
    else {
        float r = (float)maskD / (float)D;
        int mz = clampi((int)((z + 0.5f) * r), 0, maskD - 1);
        int my = clampi((int)((y + 0.5f) * r), 0, maskD - 1);
        int mx = clampi((int)((x + 0.5f) * r), 0, maskD - 1);
        m = mask[(mz * maskD + my) * maskD + mx];
    }
    if (denom > 1e-9f) {
        float sc = tau * diff / denom * m;
        vf[idx]         += sc * gz;
        vf[N + idx]     += sc * gy;
        vf[2 * N + idx] += sc * gx;
    }
}

// ---------------- fused 3-axis separable 7-tap Gaussian, zero pad; 16^3 tile, 22^3 halo
__global__ __launch_bounds__(256, 2)
void k_smooth3(const float* __restrict__ src, float* __restrict__ dst, int D)
{
    __shared__ float B1[10648];       // 22^3 staged input
    __shared__ float B2[7744];        // 16*22*22 after z-pass
    float* B3 = B1;                   // 16*16*22 after y-pass (overlays dead B1)
    int nt = D >> 4;
    int b = blockIdx.x;
    int tx = b % nt, ty = (b / nt) % nt, tz = b / (nt * nt);
    int c = blockIdx.y;
    int N = D * D * D;
    const float* s = src + (size_t)c * N;
    float* d = dst + (size_t)c * N;
    int x0 = tx * 16, y0 = ty * 16, z0 = tz * 16;
    int tid = threadIdx.x;

    for (int l = tid; l < 10648; l += 256) {
        int xx = l % 22, yy = (l / 22) % 22, zz = l / 484;
        int gz = z0 + zz - 3, gy = y0 + yy - 3, gx = x0 + xx - 3;
        float v = 0.f;
        if ((unsigned)gz < (unsigned)D && (unsigned)gy < (unsigned)D && (unsigned)gx < (unsigned)D)
            v = s[((size_t)gz * D + gy) * D + gx];
        B1[l] = v;
    }
    __syncthreads();
    for (int l = tid; l < 16 * 484; l += 256) {
        int xx = l % 22, yy = (l / 22) % 22, zo = l / 484;
        int base = (zo + 3) * 484 + yy * 22 + xx;
        B2[l] = GW0 * B1[base]
              + GW1 * (B1[base - 484] + B1[base + 484])
              + GW2 * (B1[base - 968] + B1[base + 968])
              + GW3 * (B1[base - 1452] + B1[base + 1452]);
    }
    __syncthreads();
    for (int l = tid; l < 16 * 16 * 22; l += 256) {
        int xx = l % 22, yo = (l / 22) % 16, zo = l / 352;
        int base = zo * 484 + (yo + 3) * 22 + xx;
        B3[l] = GW0 * B2[base]
              + GW1 * (B2[base - 22] + B2[base + 22])
              + GW2 * (B2[base - 44] + B2[base + 44])
              + GW3 * (B2[base - 66] + B2[base + 66]);
    }
    __syncthreads();
    for (int l = tid; l < 4096; l += 256) {
        int xo = l % 16, yo = (l / 16) % 16, zo = l / 256;
        int base = zo * 352 + yo * 22 + xo + 3;
        float a = GW0 * B3[base]
                + GW1 * (B3[base - 1] + B3[base + 1])
                + GW2 * (B3[base - 2] + B3[base + 2])
                + GW3 * (B3[base - 3] + B3[base + 3]);
        d[((size_t)(z0 + zo) * D + (y0 + yo)) * D + (x0 + xo)] = a;
    }
}

// ---------------- fused warp + pack CNN input channels-last bf16:
// [vox][8] = {vf0,vf1,vf2,img*mask,warp(moving,vf),0,0,0}
__global__ void k_pack_warp(const float* __restrict__ vf, const float* __restrict__ image,
                            const float* __restrict__ mask, const float* __restrict__ moving,
                            short* __restrict__ xin8)
{
    int i = blockIdx.x * blockDim.x + threadIdx.x;
    if (i >= N96) return;
    int x = i % D96, y = (i / D96) % D96, z = i / (D96 * D96);
    float v0 = vf[i], v1 = vf[N96 + i], v2 = vf[2 * N96 + i];
    float w = trilerp(moving, D96, z + v0, y + v1, x + v2);
    s16x8 v;
    v[0] = f2bf(v0); v[1] = f2bf(v1); v[2] = f2bf(v2);
    v[3] = f2bf(image[i] * mask[i]); v[4] = f2bf(w);
    v[5] = 0; v[6] = 0; v[7] = 0;
    *reinterpret_cast<s16x8*>(&xin8[(size_t)i * 8]) = v;
}

// ---------------- all weight reorders in one launch.
// Layout: Wr[kg][COUTP][8] bf16, k = kg*8+j, (off,ci) = (k/CINP, k%CINP), off = dz*9+dy*3+dx
__global__ void k_wreorder_all(const float* __restrict__ w1, const float* __restrict__ w2,
                               const float* __restrict__ w3, const float* __restrict__ w4,
                               short* __restrict__ r1, short* __restrict__ r2,
                               short* __restrict__ r3, short* __restrict__ r4)
{
    int i = blockIdx.x * 256 + threadIdx.x;
    const int S1 = 7168, S2 = 55296, S3 = 55296, S4 = 13824;
    const float* w; short* r; int CIN, CINP, COUT, COUTP;
    int idx = i;
    if (idx < S1)              { w = w1; r = r1; CIN = 5;  CINP = 8;  COUT = 32; COUTP = 32; }
    else if ((idx -= S1) < S2) { w = w2; r = r2; CIN = 32; CINP = 32; COUT = 64; COUTP = 64; }
    else if ((idx -= S2) < S3) { w = w3; r = r3; CIN = 64; CINP = 64; COUT = 32; COUTP = 32; }
    else if ((idx -= S3) < S4) { w = w4; r = r4; CIN = 32; CINP = 32; COUT = 3;  COUTP = 16; }
    else return;
    int j = idx & 7;
    int co = (idx >> 3) % COUTP;
    int kg = idx / (8 * COUTP);
    int k = kg * 8 + j;
    int off = k / CINP, ci = k % CINP;
    float v = 0.f;
    if (co < COUT && off < 27 && ci < CIN)
        v = w[((size_t)co * CIN + ci) * 27 + off];
    r[idx] = f2bf(v);
}

// fast mish: x * tanh(softplus(x)) == x - 2x / ((1+e^x)^2 + 1)
DEV float mishf(float f)
{
    float e = __expf(f);
    float t = 1.f + e;
    float u = t * t + 1.f;
    return f - 2.f * f * __builtin_amdgcn_rcpf(u);
}

// ---------------- conv1: 8ch input, full 3-plane tile, 32x32x16 MFMA, fused stats,
// LDS-transpose epilogue
__global__ __launch_bounds__(256, 4)
void k_conv1(const short* __restrict__ act, const short* __restrict__ Wr,
             short* __restrict__ outcl, float* __restrict__ part)
{
    constexpr int YH = 6, TN = 3, KS = 14;       // (27*8+15)/16
    constexpr int TILE_G = 3 * YH * 98;          // granules (G=1) -> 14112 shorts
    __shared__ __align__(16) short tile[TILE_G * 8];   // 28224 B (>= transpose 24576 B)
    float* red = (float*)tile;

    int b = blockIdx.x;
    int xcd = b & 7, bidx = b >> 3;
    int zblk = xcd * 12 + bidx / 24;
    int y0 = (bidx % 24) * 4;

    int tid = threadIdx.x;
    int lane = tid & 63, wave = tid >> 6;
    int ln31 = lane & 31, hi = lane >> 5;

    for (int i = tid; i < TILE_G; i += 256) {
        int xi = i % 98, yi = (i / 98) % YH, zi = i / (98 * YH);
        int gz = zblk + zi - 1, gy = y0 + yi - 1, gx = xi - 1;
        s16x8 v = {0, 0, 0, 0, 0, 0, 0, 0};
        if ((unsigned)gz < 96u && (unsigned)gy < 96u && (unsigned)gx < 96u)
            v = *reinterpret_cast<const s16x8*>(&act[(size_t)((gz * 96 + gy) * 96 + gx) * 8]);
        *reinterpret_cast<s16x8*>(&tile[i * 8]) = v;
    }
    __syncthreads();

    f32x16 acc[TN];
    #pragma unroll
    for (int i = 0; i < TN; ++i)
        #pragma unroll
        for (int e = 0; e < 16; ++e) acc[i][e] = 0.f;

    int xb_[TN];
    #pragma unroll
    for (int i = 0; i < TN; ++i) xb_[i] = i * 32 + ln31;

    #pragma unroll
    for (int ks = 0; ks < KS; ++ks) {
        s16x8 a = *reinterpret_cast<const s16x8*>(&Wr[((size_t)(ks * 2 + hi) * 32 + ln31) * 8]);
        int off = ks * 2 + hi; if (off > 26) off = 26;   // padded k: weights are 0
        int dz = off / 9, r9 = off - dz * 9, dy = r9 / 3, dx = r9 - dy * 3;
        #pragma unroll
        for (int i = 0; i < TN; ++i) {
            int gi = (dz * YH + wave + dy) * 98 + xb_[i] + dx;
            s16x8 bf = *reinterpret_cast<const s16x8*>(&tile[gi * 8]);
            acc[i] = __builtin_amdgcn_mfma_f32_32x32x16_bf16(a, bf, acc[i], 0, 0, 0);
        }
    }

    // stats (shfl over ln31)
    float st_s[16], st_q[16];
    #pragma unroll
    for (int j = 0; j < 16; ++j) { st_s[j] = 0.f; st_q[j] = 0.f; }
    #pragma unroll
    for (int i = 0; i < TN; ++i)
        #pragma unroll
        for (int e = 0; e < 16; ++e) {
            float v = acc[i][e];
            st_s[e] += v; st_q[e] += v * v;
        }
    #pragma unroll
    for (int j = 0; j < 16; ++j) {
        #pragma unroll
        for (int o = 1; o <= 16; o <<= 1) {
            st_s[j] += __shfl_xor(st_s[j], o);
            st_q[j] += __shfl_xor(st_q[j], o);
        }
    }

    // transpose epilogue: acc -> LDS [row][x][ch] (swizzled) -> coalesced stores
    __syncthreads();
    #pragma unroll
    for (int i = 0; i < TN; ++i) {
        int x = xb_[i];
        #pragma unroll
        for (int q = 0; q < 4; ++q) {
            s16x4 pk;
            #pragma unroll
            for (int r = 0; r < 4; ++r) pk[r] = f2bf(acc[i][q * 4 + r]);
            int bo = (((wave * 96 + x) * 32 + q * 8 + hi * 4) * 2) ^ ((x & 3) << 4);
            *reinterpret_cast<s16x4*>((char*)tile + bo) = pk;
        }
    }
    __syncthreads();
    for (int t = tid; t < 4 * 96 * 4; t += 256) {
        int gran = t & 3;
        int x = (t >> 2) % 96;
        int row = t / (4 * 96);
        int bo = (((row * 96 + x) * 32) * 2 + gran * 16) ^ ((x & 3) << 4);
        s16x8 v = *reinterpret_cast<const s16x8*>((char*)tile + bo);
        int vox = ((zblk * 96) + y0 + row) * 96 + x;
        *reinterpret_cast<s16x8*>(&outcl[(size_t)vox * 32 + gran * 8]) = v;
    }

    // block-level stats reduce via LDS overlay
    __syncthreads();
    if (ln31 == 0) {
        int base = (wave * 2 + hi) * 16;
        #pragma unroll
        for (int j = 0; j < 16; ++j) {
            red[(base + j) * 2]     = st_s[j];
            red[(base + j) * 2 + 1] = st_q[j];
        }
    }
    __syncthreads();
    if (tid < 64) {
        int c = tid >> 1, sel = tid & 1;
        int q = (c >> 3) & 3, hic = (c >> 2) & 1, r = c & 3;
        int j = q * 4 + r;
        float v = 0.f;
        #pragma unroll
        for (int w = 0; w < 4; ++w)
            v += red[((w * 2 + hic) * 16 + j) * 2 + sel];
        part[((size_t)c * gridDim.x + blockIdx.x) * 2 + sel] = v;
    }
}

// ---------------- conv2: 32->64, XCD-aligned paired cout-half blocks, 32B-pair staging,
// register-precomputed B addresses (ds_read imm offsets for dy)
__global__ __launch_bounds__(256, 4)
void k_conv_c2(const short* __restrict__ act, const short* __restrict__ Wr,
               short* __restrict__ outcl, float* __restrict__ part)
{
    constexpr int TN = 3, YH = 6;
    __shared__ __align__(16) short tile[YH * 98 * 32];   // 37632 B (>= TR 24576 B)
    float* red = (float*)tile;

    int bb = blockIdx.x;
    int xcd = bb & 7;                         // physical XCD (hw round-robin)
    int ch = (bb >> 3) & 1;                   // cout half; bb and bb+8 share a tile + XCD
    int idx = bb >> 4;                        // tile within slab, 0..287
    int zblk = xcd * 12 + idx / 24;
    int y0 = (idx % 24) * 4;
    int tileid = xcd * 288 + idx;             // 0..2303 for stats partials

    int tid = threadIdx.x;
    int lane = tid & 63, wave = tid >> 6;
    int ln31 = lane & 31, hi = lane >> 5;

    int xb_[TN];
    #pragma unroll
    for (int i = 0; i < TN; ++i) xb_[i] = i * 32 + ln31;

    // precomputed B-tile byte addresses (dy=0); dy adds imm offset dy*6272
    int baddr[TN][3][2];
    #pragma unroll
    for (int i = 0; i < TN; ++i)
        #pragma unroll
        for (int dx = 0; dx < 3; ++dx) {
            int xi = xb_[i] + dx;
            int sw = (xi >> 1) & 3;
            #pragma unroll
            for (int gs = 0; gs < 2; ++gs)
                baddr[i][dx][gs] = ((wave * 98 + xi) * 4 + ((gs * 2 + hi) ^ sw)) * 16;
        }

    f32x16 acc[TN];
    #pragma unroll
    for (int i = 0; i < TN; ++i)
        #pragma unroll
        for (int e = 0; e < 16; ++e) acc[i][e] = 0.f;

    for (int p = 0; p < 3; ++p) {
        int gz = zblk + p - 1;
        __syncthreads();
        // stage 6x98 x 32ch plane, 32B (2 granules) per lane-iter
        #pragma unroll
        for (int it = 0; it < 5; ++it) {
            int i = it * 256 + tid;
            if (i < 1176) {
                int g2 = i & 1, x2 = i >> 1;
                int xi = x2 % 98, yi = x2 / 98;
                int gy = y0 + yi - 1, gx = xi - 1;
                s16x8 v0 = {0, 0, 0, 0, 0, 0, 0, 0}, v1 = v0;
                if ((unsigned)gz < 96u && (unsigned)gy < 96u && (unsigned)gx < 96u) {
                    const short* sp = &act[(size_t)((gz * 96 + gy) * 96 + gx) * 32 + g2 * 16];
                    v0 = *reinterpret_cast<const s16x8*>(sp);
                    v1 = *reinterpret_cast<const s16x8*>(sp + 8);
                }
                int s0 = (g2 * 2) ^ ((xi >> 1) & 3);
                short* dp = &tile[((yi * 98 + xi) << 2) * 8];
                *reinterpret_cast<s16x8*>(&dp[s0 * 8]) = v0;
                *reinterpret_cast<s16x8*>(&dp[(s0 ^ 1) * 8]) = v1;
            }
        }
        __syncthreads();
        int kgbase = p * 36;
        #pragma unroll
        for (int ks = 0; ks < 18; ++ks) {
            constexpr int offt[18] = {0,0,1,1,2,2,3,3,4,4,5,5,6,6,7,7,8,8};
            const int off = offt[ks], gs = ks & 1;
            int kg = kgbase + off * 4 + gs * 2 + hi;
            s16x8 A = *reinterpret_cast<const s16x8*>(
                &Wr[((size_t)kg * 64 + ch * 32 + ln31) * 8]);
            const int dy = off / 3, dx = off % 3;
            #pragma unroll
            for (int i = 0; i < TN; ++i) {
                s16x8 bf = *reinterpret_cast<const s16x8*>(
                    (const char*)tile + baddr[i][dx][gs] + dy * 6272);
                acc[i] = __builtin_amdgcn_mfma_f32_32x32x16_bf16(A, bf, acc[i], 0, 0, 0);
            }
        }
    }

    // stats; local channel = (e&3) + 8*(e>>2) + 4*hi
    float st_s[16], st_q[16];
    #pragma unroll
    for (int j = 0; j < 16; ++j) { st_s[j] = 0.f; st_q[j] = 0.f; }
    #pragma unroll
    for (int i = 0; i < TN; ++i)
        #pragma unroll
        for (int e = 0; e < 16; ++e) {
            float v = acc[i][e];
            st_s[e] += v; st_q[e] += v * v;
        }
    #pragma unroll
    for (int j = 0; j < 16; ++j) {
        #pragma unroll
        for (int o = 1; o <= 16; o <<= 1) {
            st_s[j] += __shfl_xor(st_s[j], o);
            st_q[j] += __shfl_xor(st_q[j], o);
        }
    }

    // transpose epilogue -> coalesced 64B/vox-half stores
    __syncthreads();
    #pragma unroll
    for (int i = 0; i < TN; ++i) {
        int x = xb_[i];
        #pragma unroll
        for (int q = 0; q < 4; ++q) {
            s16x4 pk;
            #pragma unroll
            for (int r = 0; r < 4; ++r) pk[r] = f2bf(acc[i][q * 4 + r]);
            int bo = (((wave * 96 + x) * 32 + q * 8 + hi * 4) * 2) ^ ((x & 3) << 4);
            *reinterpret_cast<s16x4*>((char*)tile + bo) = pk;
        }
    }
    __syncthreads();
    for (int t = tid; t < 4 * 96 * 4; t += 256) {
        int gran = t & 3;
        int x = (t >> 2) % 96;
        int row = t / (4 * 96);
        int bo = (((row * 96 + x) * 32) * 2 + gran * 16) ^ ((x & 3) << 4);
        s16x8 v = *reinterpret_cast<const s16x8*>((char*)tile + bo);
        int vox = ((zblk * 96) + y0 + row) * 96 + x;
        *reinterpret_cast<s16x8*>(&outcl[(size_t)vox * 64 + ch * 32 + gran * 8]) = v;
    }

    // block-level stats reduce
    __syncthreads();
    if (ln31 == 0) {
        int base = (wave * 2 + hi) * 16;
        #pragma unroll
        for (int j = 0; j < 16; ++j) {
            red[(base + j) * 2]     = st_s[j];
            red[(base + j) * 2 + 1] = st_q[j];
        }
    }
    __syncthreads();
    if (tid < 64) {
        int c = tid >> 1, sel = tid & 1;
        int q = (c >> 3) & 3, hic = (c >> 2) & 1, r = c & 3;
        int j = q * 4 + r;
        float v = 0.f;
        #pragma unroll
        for (int w = 0; w < 4; ++w)
            v += red[((w * 2 + hic) * 16 + j) * 2 + sel];
        part[((size_t)(ch * 32 + c) * 2304 + tileid) * 2 + sel] = v;
    }
}

// ---------------- conv3: 64->32, XCD-aligned paired cout-half blocks, 16x16x32 MFMA,
// 32B-pair staging + register-precomputed B addresses
__global__ __launch_bounds__(256, 4)
void k_conv_c3(const short* __restrict__ act, const short* __restrict__ Wr,
               short* __restrict__ outcl, float* __restrict__ part)
{
    constexpr int YH = 6;
    __shared__ __align__(16) short tile[YH * 98 * 32];   // 37632 B (>= TR 12288 B)
    float* red = (float*)tile;

    int bb = blockIdx.x;
    int xcd = bb & 7;                         // physical XCD
    int ch = (bb >> 3) & 1;                   // cout half (16 couts)
    int idx = bb >> 4;
    int zblk = xcd * 12 + idx / 24;
    int y0 = (idx % 24) * 4;
    int tileid = xcd * 288 + idx;

    int tid = threadIdx.x;
    int lane = tid & 63, wave = tid >> 6;
    int ln15 = lane & 15, lg = lane >> 4;

    // precomputed B-tile byte addresses (dy via imm offset)
    int baddr[6][3];
    #pragma unroll
    for (int i = 0; i < 6; ++i)
        #pragma unroll
        for (int dx = 0; dx < 3; ++dx) {
            int xi = i * 16 + ln15 + dx;
            baddr[i][dx] = ((wave * 98 + xi) * 4 + (lg ^ ((xi >> 1) & 3))) * 16;
        }

    f32x4 acc[6];
    #pragma unroll
    for (int i = 0; i < 6; ++i) acc[i] = {0.f, 0.f, 0.f, 0.f};

    for (int p = 0; p < 3; ++p) {
        int gz = zblk + p - 1;
        for (int h = 0; h < 2; ++h) {
            __syncthreads();
            #pragma unroll
            for (int it = 0; it < 5; ++it) {
                int i = it * 256 + tid;
                if (i < 1176) {
                    int g2 = i & 1, x2 = i >> 1;
                    int xi = x2 % 98, yi = x2 / 98;
                    int gy = y0 + yi - 1, gx = xi - 1;
                    s16x8 v0 = {0, 0, 0, 0, 0, 0, 0, 0}, v1 = v0;
                    if ((unsigned)gz < 96u && (unsigned)gy < 96u && (unsigned)gx < 96u) {
                        const short* sp = &act[(size_t)((gz * 96 + gy) * 96 + gx) * 64
                                               + (h * 4 + g2 * 2) * 8];
                        v0 = *reinterpret_cast<const s16x8*>(sp);
                        v1 = *reinterpret_cast<const s16x8*>(sp + 8);
                    }
                    int s0 = (g2 * 2) ^ ((xi >> 1) & 3);
                    short* dp = &tile[((yi * 98 + xi) << 2) * 8];
                    *reinterpret_cast<s16x8*>(&dp[s0 * 8]) = v0;
                    *reinterpret_cast<s16x8*>(&dp[(s0 ^ 1) * 8]) = v1;
                }
            }
            __syncthreads();
            #pragma unroll
            for (int off = 0; off < 9; ++off) {
                int kg = (p * 9 + off) * 8 + h * 4 + lg;
                s16x8 A = *reinterpret_cast<const s16x8*>(
                    &Wr[((size_t)kg * 32 + ch * 16 + ln15) * 8]);
                const int dy = off / 3, dx = off % 3;
                #pragma unroll
                for (int i = 0; i < 6; ++i) {
                    s16x8 bf = *reinterpret_cast<const s16x8*>(
                        (const char*)tile + baddr[i][dx] + dy * 6272);
                    acc[i] = __builtin_amdgcn_mfma_f32_16x16x32_bf16(A, bf, acc[i], 0, 0, 0);
                }
            }
        }
    }

    // stats; local channel = lg*4 + r; reduce over the 16 vox lanes (ln15)
    float st_s[4], st_q[4];
    #pragma unroll
    for (int j = 0; j < 4; ++j) { st_s[j] = 0.f; st_q[j] = 0.f; }
    #pragma unroll
    for (int i = 0; i < 6; ++i)
        #pragma unroll
        for (int r = 0; r < 4; ++r) {
            float v = acc[i][r];
            st_s[r] += v; st_q[r] += v * v;
        }
    #pragma unroll
    for (int j = 0; j < 4; ++j) {
        #pragma unroll
        for (int o = 1; o <= 8; o <<= 1) {
            st_s[j] += __shfl_xor(st_s[j], o);
            st_q[j] += __shfl_xor(st_q[j], o);
        }
    }

    // transpose epilogue: [row][x][16ch] swizzled -> coalesced 32B/vox stores (paired halves)
    __syncthreads();
    #pragma unroll
    for (int i = 0; i < 6; ++i) {
        int x = i * 16 + ln15;
        s16x4 pk;
        #pragma unroll
        for (int r = 0; r < 4; ++r) pk[r] = f2bf(acc[i][r]);
        int bo = (((wave * 96 + x) * 16 + lg * 4) * 2) ^ ((x & 3) << 4);
        *reinterpret_cast<s16x4*>((char*)tile + bo) = pk;
    }
    __syncthreads();
    for (int t = tid; t < 4 * 96 * 2; t += 256) {
        int gran = t & 1;
        int x = (t >> 1) % 96;
        int row = t / (2 * 96);
        int bo = (((row * 96 + x) * 16) * 2 + gran * 16) ^ ((x & 3) << 4);
        s16x8 v = *reinterpret_cast<const s16x8*>((char*)tile + bo);
        int vox = ((zblk * 96) + y0 + row) * 96 + x;
        *reinterpret_cast<s16x8*>(&outcl[(size_t)vox * 32 + ch * 16 + gran * 8]) = v;
    }

    // block-level stats reduce: red[wave][lg][4]
    __syncthreads();
    if (ln15 == 0) {
        int base = (wave * 4 + lg) * 4;
        #pragma unroll
        for (int j = 0; j < 4; ++j) {
            red[(base + j) * 2]     = st_s[j];
            red[(base + j) * 2 + 1] = st_q[j];
        }
    }
    __syncthreads();
    if (tid < 32) {
        int c = tid >> 1, sel = tid & 1;     // c = local channel 0..15 = lg*4+r
        float v = 0.f;
        #pragma unroll
        for (int w = 0; w < 4; ++w)
            v += red[((w * 4 + (c >> 2)) * 4 + (c & 3)) * 2 + sel];
        part[((size_t)(ch * 16 + c) * 2304 + tileid) * 2 + sel] = v;
    }
}

// ---------------- conv4: 32->3 via 16x16x32 MFMA (COUTP=16), 32B staging + precomp addrs,
// fused vf-add + vf copy
__global__ __launch_bounds__(256, 4)
void k_conv4(const short* __restrict__ act, const short* __restrict__ Wr,
             const float* __restrict__ bias, const float* __restrict__ vf,
             float* __restrict__ corr, float* __restrict__ outvf)
{
    constexpr int YH = 6;
    __shared__ __align__(16) short tile[YH * 98 * 32];

    int b = blockIdx.x;
    int xcd = b & 7, bidx = b >> 3;
    int zblk = xcd * 12 + bidx / 24;
    int y0 = (bidx % 24) * 4;

    int tid = threadIdx.x;
    int lane = tid & 63, wave = tid >> 6;
    int ln15 = lane & 15, lg = lane >> 4;

    int baddr[6][3];
    #pragma unroll
    for (int i = 0; i < 6; ++i)
        #pragma unroll
        for (int dx = 0; dx < 3; ++dx) {
            int xi = i * 16 + ln15 + dx;
            baddr[i][dx] = ((wave * 98 + xi) * 4 + (lg ^ ((xi >> 1) & 3))) * 16;
        }

    f32x4 acc[6];
    #pragma unroll
    for (int i = 0; i < 6; ++i) acc[i] = {0.f, 0.f, 0.f, 0.f};

    for (int p = 0; p < 3; ++p) {
        int gz = zblk + p - 1;
        __syncthreads();
        #pragma unroll
        for (int it = 0; it < 5; ++it) {
            int i = it * 256 + tid;
            if (i < 1176) {
                int g2 = i & 1, x2 = i >> 1;
                int xi = x2 % 98, yi = x2 / 98;
                int gy = y0 + yi - 1, gx = xi - 1;
                s16x8 v0 = {0, 0, 0, 0, 0, 0, 0, 0}, v1 = v0;
                if ((unsigned)gz < 96u && (unsigned)gy < 96u && (unsigned)gx < 96u) {
                    const short* sp = &act[(size_t)((gz * 96 + gy) * 96 + gx) * 32 + g2 * 16];
                    v0 = *reinterpret_cast<const s16x8*>(sp);
                    v1 = *reinterpret_cast<const s16x8*>(sp + 8);
                }
                int s0 = (g2 * 2) ^ ((xi >> 1) & 3);
                short* dp = &tile[((yi * 98 + xi) << 2) * 8];
                *reinterpret_cast<s16x8*>(&dp[s0 * 8]) = v0;
                *reinterpret_cast<s16x8*>(&dp[(s0 ^ 1) * 8]) = v1;
            }
        }
        __syncthreads();
        #pragma unroll
        for (int ks = 0; ks < 9; ++ks) {
            int kg = (p * 9 + ks) * 4 + lg;
            s16x8 a = *reinterpret_cast<const s16x8*>(&Wr[((size_t)kg * 16 + ln15) * 8]);
            const int dy = ks / 3, dx = ks % 3;
            #pragma unroll
            for (int i = 0; i < 6; ++i) {
                s16x8 bf = *reinterpret_cast<const s16x8*>(
                    (const char*)tile + baddr[i][dx] + dy * 6272);
                acc[i] = __builtin_amdgcn_mfma_f32_16x16x32_bf16(a, bf, acc[i], 0, 0, 0);
            }
        }
    }
    // D: col=ln15 (vox), row = lg*4 + r (cout). Rows 0..2 live on lg==0.
    if (lg == 0) {
        #pragma unroll
        for (int i = 0; i < 6; ++i) {
            int vox = ((zblk * 96) + y0 + wave) * 96 + i * 16 + ln15;
            #pragma unroll
            for (int r = 0; r < 3; ++r) {
                float v = vf[(size_t)r * N96 + vox];
                corr[(size_t)r * N96 + vox] = acc[i][r] + bias[r] + v;
                outvf[(size_t)r * N96 + vox] = v;
            }
        }
    }
}

// ---------------- instance-norm apply + mish, channels-last, in place
template <int C>
__global__ void k_norm_mish_cl(short* __restrict__ x, const float* __restrict__ stats)
{
    constexpr int G8 = C / 8;
    int gt = blockIdx.x * 256 + threadIdx.x;
    int cg = threadIdx.x % G8;       // fixed per thread (stride divisible by G8)
    float mean[8], inv[8];
    #pragma unroll
    for (int j = 0; j < 8; ++j) { mean[j] = stats[2 * (cg * 8 + j)]; inv[j] = stats[2 * (cg * 8 + j) + 1]; }
    const int TGn = N96 * G8;
    int stride = gridDim.x * 256;
    for (int i = gt; i < TGn; i += stride) {
        s16x8 v = *reinterpret_cast<const s16x8*>(&x[(size_t)i * 8]);
        #pragma unroll
        for (int j = 0; j < 8; ++j)
            v[j] = f2bf(mishf((bf2f(v[j]) - mean[j]) * inv[j]));
        *reinterpret_cast<s16x8*>(&x[(size_t)i * 8]) = v;
    }
}

// stage 2: reduce per-block partials/channel -> mean + inv_std
__global__ void k_stats_reduce(const float* __restrict__ part, float* __restrict__ stats,
                               int G, int N)
{
    int c = blockIdx.x;
    int t = threadIdx.x;
    float s = 0.f, s2 = 0.f;
    for (int i = t; i < G; i += blockDim.x) {
        s  += part[((size_t)c * G + i) * 2];
        s2 += part[((size_t)c * G + i) * 2 + 1];
    }
    #pragma unroll
    for (int o = 32; o > 0; o >>= 1) { s += __shfl_down(s, o); s2 += __shfl_down(s2, o); }
    __shared__ float a[4], b[4];
    int lane = t & 63, wid = t >> 6;
    if (lane == 0) { a[wid] = s; b[wid] = s2; }
    __syncthreads();
    if (t == 0) {
        float ss = a[0] + a[1] + a[2] + a[3];
        float qq = b[0] + b[1] + b[2] + b[3];
        float mean = ss / (float)N;
        float var = qq / (float)N - mean * mean;
        stats[2 * c] = mean;
        stats[2 * c + 1] = rsqrtf(var + 1e-5f);
    }
}

extern "C" void kernel_launch(void* const* d_in, const int* in_sizes, int n_in,
                              void* d_out, int out_size, void* d_ws, size_t ws_size,
                              hipStream_t stream)
{
    const float* image   = (const float*)d_in[0];
    const float* mask    = (const float*)d_in[1];
    const float* moving  = (const float*)d_in[2];
    const float* spacing = (const float*)d_in[3];
    const float* w1 = (const float*)d_in[4];
    const float* w2 = (const float*)d_in[5];
    const float* w3 = (const float*)d_in[6];
    const float* w4 = (const float*)d_in[7];
    const float* b4 = (const float*)d_in[8];
    float* out = (float*)d_out;

    char* ws = (char*)d_ws;
    size_t off = 0;
    auto alloc = [&](size_t bytes) -> char* {
        char* p = ws + off;
        off += (bytes + 255) & ~(size_t)255;
        return p;
    };
    float* f48   = (float*)alloc((size_t)N48 * 4);
    float* mv48  = (float*)alloc((size_t)N48 * 4);
    float* vfA48 = (float*)alloc((size_t)3 * N48 * 4);
    float* vfB48 = (float*)alloc((size_t)3 * N48 * 4);
    float* wrp48 = (float*)alloc((size_t)N48 * 4);
    float* vfA96 = (float*)alloc((size_t)3 * N96 * 4);
    float* vfB96 = (float*)alloc((size_t)3 * N96 * 4);
    float* vfC96 = (float*)alloc((size_t)3 * N96 * 4);
    float* wrp96 = (float*)alloc((size_t)N96 * 4);
    short* xin8  = (short*)alloc((size_t)8 * N96 * 2);
    short* y1    = (short*)alloc((size_t)32 * N96 * 2);
    short* y2    = (short*)alloc((size_t)64 * N96 * 2);
    short* wr1   = (short*)alloc((size_t)7168 * 2);
    short* wr2   = (short*)alloc((size_t)55296 * 2);
    short* wr3   = (short*)alloc((size_t)55296 * 2);
    short* wr4   = (short*)alloc((size_t)13824 * 2);
    float* part  = (float*)alloc((size_t)64 * 2304 * 2 * 4);
    float* stats = (float*)alloc((size_t)64 * 2 * 4);

    const int B = 256;
    const int g48  = (N48 + B - 1) / B;
    const int g96  = (N96 + B - 1) / B;
    const int g96c = (3 * N96 + B - 1) / B;

    // ---- all weight reorders (one launch) ----
    k_wreorder_all<<<(131584 + 255) / 256, B, 0, stream>>>(w1, w2, w3, w4, wr1, wr2, wr3, wr4);

    // ---- Level 0 (48^3) ----
    k_downsample2x2<<<dim3(g48, 2), B, 0, stream>>>(image, moving, f48, mv48);
    hipMemsetAsync(vfA48, 0, (size_t)3 * N48 * 4, stream);
    float* cur = vfA48; float* oth = vfB48;
    for (int it = 0; it < 2; ++it) {
        k_warp<<<g48, B, 0, stream>>>(mv48, cur, wrp48, D48);
        k_forces<<<g48, B, 0, stream>>>(wrp48, f48, mask, spacing, cur, D48, D96, 2.0f);
        k_smooth3<<<dim3(27, 3), B, 0, stream>>>(cur, oth, D48);
        float* tmp = cur; cur = oth; oth = tmp;
    }

    // ---- Level 1 (96^3) ----
    k_upsample_vf<<<g96c, B, 0, stream>>>(cur, vfA96);
    float* cur9 = vfA96; float* oth9 = vfB96;
    for (int it = 0; it < 2; ++it) {
        k_warp<<<g96, B, 0, stream>>>(moving, cur9, wrp96, D96);
        k_forces<<<g96, B, 0, stream>>>(wrp96, image, mask, spacing, cur9, D96, D96, 2.0f);
        k_smooth3<<<dim3(216, 3), B, 0, stream>>>(cur9, oth9, D96);
        float* tmp = cur9; cur9 = oth9; oth9 = tmp;
    }
    // cur9 == vfA96 here (final vf)

    // ---- CNN ----
    k_pack_warp<<<g96, B, 0, stream>>>(cur9, image, mask, moving, xin8);

    // conv1: 8(5)->32, stats fused; then reduce + norm
    k_conv1<<<2304, B, 0, stream>>>(xin8, wr1, y1, part);
    k_stats_reduce<<<32, B, 0, stream>>>(part, stats, 2304, N96);
    k_norm_mish_cl<32><<<2048, B, 0, stream>>>(y1, stats);

    // conv2: 32->64, XCD-aligned paired cout-half blocks
    k_conv_c2<<<4608, B, 0, stream>>>(y1, wr2, y2, part);
    k_stats_reduce<<<64, B, 0, stream>>>(part, stats, 2304, N96);
    k_norm_mish_cl<64><<<2048, B, 0, stream>>>(y2, stats);

    // conv3: 64->32, XCD-aligned paired cout-half blocks (output reuses y1)
    k_conv_c3<<<4608, B, 0, stream>>>(y2, wr3, y1, part);
    k_stats_reduce<<<32, B, 0, stream>>>(part, stats, 2304, N96);
    k_norm_mish_cl<32><<<2048, B, 0, stream>>>(y1, stats);

    // conv4: 32->3 (+bias), f32 out = correction + vf; also emits vf output copy
    k_conv4<<<2304, B, 0, stream>>>(y1, wr4, b4, cur9, vfC96, out + (size_t)4 * N96);

    // corrected_vf = smooth3d(vf + correction) -> straight to d_out
    k_smooth3<<<dim3(216, 3), B, 0, stream>>>(vfC96, out + N96, D96);

    // corrected_warped_moving
    k_warp<<<g96, B, 0, stream>>>(moving, out + N96, out, D96);
}